// Round 1
// 249.161 us; speedup vs baseline: 1.0027x; 1.0027x over previous
//
#include <hip/hip_runtime.h>
#include <math.h>

// Problem constants (from reference setup_inputs)
#define S20 20
#define BB 1024
#define LL 512
#define HH 2
#define KK 2
#define NRATES 100000
#define NTERM 10   // highest Taylor power: P = sum_{n=0}^{NTERM} tau^n * Q^n/n!

__device__ __forceinline__ float softplusf(float x) {
    // stable log1p(exp(x)); matches jax.nn.softplus for our range
    if (x > 20.f) return x;
    return log1pf(expf(x));
}

// ---------------------------------------------------------------------------
// Kernel 1: per (h,k) build normalized GTR rate matrix Q, then coefficient
// matrices C_n = Q^n / n! for n = 0..NTERM into d_ws:
//   qpow[ hk ][ n ][ i*20+j ],  hk = h*K + k   (4 * 11 * 400 floats = 70.4 KB)
// ---------------------------------------------------------------------------
__global__ __launch_bounds__(256) void build_qpow(
        const float* __restrict__ exch,   // (H,K,20,20)
        const float* __restrict__ eq,     // (H,K,20)
        float* __restrict__ qpow) {
    __shared__ float p[S20];
    __shared__ float row[S20];
    __shared__ float mue_s;
    __shared__ float Qm[400];
    __shared__ float bufA[400];
    __shared__ float bufB[400];

    const int hk = blockIdx.x;      // h*K + k
    const int tid = threadIdx.x;

    // equilibrium distribution p = softmax(eq[h,k,:])  (tiny: thread 0 serial)
    if (tid == 0) {
        const float* e = eq + hk * S20;
        float m = -1e30f;
        for (int i = 0; i < S20; i++) m = fmaxf(m, e[i]);
        float s = 0.f;
        for (int i = 0; i < S20; i++) { float v = expf(e[i] - m); p[i] = v; s += v; }
        float inv = 1.f / s;
        for (int i = 0; i < S20; i++) p[i] *= inv;
    }
    __syncthreads();

    // R_ij = softplus(0.5*(K_ij + K_ji)) off-diag, 0 on diag;  Qm = R_ij * p_j
    const float* ek = exch + hk * 400;
    for (int e = tid; e < 400; e += 256) {
        int i = e / 20, j = e % 20;
        float r = 0.f;
        if (i != j) r = softplusf(0.5f * (ek[i * 20 + j] + ek[j * 20 + i]));
        Qm[e] = r * p[j];
    }
    __syncthreads();

    if (tid < S20) {
        float s = 0.f;
        for (int j = 0; j < S20; j++) s += Qm[tid * 20 + j];
        row[tid] = s;
    }
    __syncthreads();
    if (tid == 0) {
        float m = 0.f;
        for (int i = 0; i < S20; i++) m += p[i] * row[i];
        mue_s = fmaxf(m, 1e-16f);
    }
    __syncthreads();

    const float inv_mue = 1.f / mue_s;
    for (int e = tid; e < 400; e += 256) {
        int i = e / 20, j = e % 20;
        float q = Qm[e];
        if (i == j) q -= row[i];     // diagonal: 0 - row_i
        Qm[e] = q * inv_mue;
    }
    __syncthreads();

    float* outb = qpow + (size_t)hk * (NTERM + 1) * 400;
    // C0 = I, C1 = Q
    for (int e = tid; e < 400; e += 256) {
        int i = e / 20, j = e % 20;
        outb[e]        = (i == j) ? 1.f : 0.f;
        outb[400 + e]  = Qm[e];
        bufA[e]        = Qm[e];
    }
    __syncthreads();

    float* cur = bufA;
    float* nxt = bufB;
    for (int n = 2; n <= NTERM; n++) {
        float invn = 1.f / (float)n;
        for (int e = tid; e < 400; e += 256) {
            int i = e / 20, j = e % 20;
            float acc = 0.f;
#pragma unroll
            for (int s = 0; s < S20; s++)
                acc += cur[i * 20 + s] * Qm[s * 20 + j];
            acc *= invn;
            nxt[e] = acc;
            outb[(size_t)n * 400 + e] = acc;
        }
        __syncthreads();
        float* t = cur; cur = nxt; nxt = t;
    }
}

// ---------------------------------------------------------------------------
// Kernel 2: one block of 320 threads (5 waves) per sequence b.
//   320 = 16 * 20 so the write loop decomposes statically:
//     r  = tid % 20   (which float4 within a sequence position l)  -- FIXED
//     hk = r / 5, h = r / 10, s4 = r % 5                           -- FIXED
//   Per-iteration work is then just: LDS z (broadcast), one v_mad for the
//   P row address, ds_read_b128, coalesced global_store_dwordx4.
//  Phases:
//   B. z[l,h] = argmax of one-hot input row (issued FIRST so global loads
//      overlap the Horner arithmetic below)
//   A. P[h][k] = Horner(tau[h]; C_0..C_N)  (qpow is 70 KB, L2-resident)
//   C. out[b,l,h,k,:] = P[h][k][z,:]  -- f = it*320 + tid, lane-consecutive
// ---------------------------------------------------------------------------
__global__ __launch_bounds__(320) void anc_probs(
        const float* __restrict__ inputs,       // (B,L,H,20)
        const int*   __restrict__ rate_indices, // (B,H)
        const float* __restrict__ tau_kernel,   // (H,NRATES)
        const float* __restrict__ qpow,         // (4,NTERM+1,400)
        float* __restrict__ out) {              // (B,L,H,K,20)
    __shared__ __align__(16) float P[4 * 400];
    __shared__ int zb[LL * HH];

    const int b = blockIdx.x;
    const int tid = threadIdx.x;

    // tau computed redundantly by every thread (2 broadcast loads each;
    // avoids an extra barrier before the Horner phase)
    const int r0 = rate_indices[b * HH + 0];
    const int r1 = rate_indices[b * HH + 1];
    const float tau0 = softplusf(tau_kernel[0 * NRATES + r0]);
    const float tau1 = softplusf(tau_kernel[1 * NRATES + r1]);

    // Phase B: argmax of each one-hot row (l,h): r = l*H + h, 5 float4 per row.
    // Issued first so the HBM loads are in flight during Horner.
    const float* inB = inputs + (size_t)b * LL * HH * S20;
    for (int r = tid; r < LL * HH; r += 320) {
        const float4* rp = (const float4*)(inB + r * S20);
        int z = 0;
#pragma unroll
        for (int q = 0; q < 5; q++) {
            float4 v = rp[q];
            int base = q * 4;
            if (v.x > 0.5f) z = base;
            if (v.y > 0.5f) z = base + 1;
            if (v.z > 0.5f) z = base + 2;
            if (v.w > 0.5f) z = base + 3;
        }
        zb[r] = z;
    }

    // Phase A: P via Horner over the 11 coefficient matrices (1600 elems,
    // exactly 5 per thread). hk = e/400, h = hk>>1.
    for (int e = tid; e < 1600; e += 320) {
        int hk = e / 400;
        float tau = (hk < 2) ? tau0 : tau1;
        const float* cb = qpow + (size_t)hk * (NTERM + 1) * 400 + (e % 400);
        float acc = cb[NTERM * 400];
#pragma unroll
        for (int n = NTERM - 1; n >= 0; n--)
            acc = acc * tau + cb[n * 400];
        P[e] = acc;
    }
    __syncthreads();   // single barrier: zb and P both ready

    // Phase C: 10240 float4 stores, 32 iterations, all index math hoisted.
    const int r  = tid % 20;        // float4 slot within one l (FIXED)
    const int h  = r / 10;          // FIXED
    const float* Prow = P + (r / 5) * 400 + (r % 5) * 4;  // + z*20 at runtime
    float4* outB = (float4*)(out + (size_t)b * LL * HH * KK * S20);

    int l = tid / 20;               // 16 l-values per iteration
    int f = tid;                    // f = l*20 + r == it*320 + tid
#pragma unroll 8
    for (int it = 0; it < 32; ++it) {
        int z = zb[l * HH + h];                       // LDS broadcast read
        float4 v = *(const float4*)(Prow + z * 20);   // ds_read_b128, 16B-aligned
        outB[f] = v;                                  // coalesced dwordx4 store
        l += 16;
        f += 320;
    }
}

extern "C" void kernel_launch(void* const* d_in, const int* in_sizes, int n_in,
                              void* d_out, int out_size, void* d_ws, size_t ws_size,
                              hipStream_t stream) {
    const float* inputs       = (const float*)d_in[0];
    const int*   rate_indices = (const int*)  d_in[1];
    const float* tau_kernel   = (const float*)d_in[2];
    const float* exch         = (const float*)d_in[3];
    const float* eq           = (const float*)d_in[4];
    float* out  = (float*)d_out;
    float* qpow = (float*)d_ws;   // needs 4*(NTERM+1)*400*4 = 70,400 B

    build_qpow<<<dim3(HH * KK), dim3(256), 0, stream>>>(exch, eq, qpow);
    anc_probs<<<dim3(BB), dim3(320), 0, stream>>>(inputs, rate_indices,
                                                  tau_kernel, qpow, out);
}